// Round 7
// baseline (203.569 us; speedup 1.0000x reference)
//
#include <hip/hip_runtime.h>

#define IN_F   4096
#define ROWS   128     // rows per block-tile; grid = 4 n-blocks x 256 tiles

typedef float vf4 __attribute__((ext_vector_type(4)));

// Direct-to-register Monarch: no LDS, no DMA. Block = 4 waves, all on diagonal
// block n; wave rq owns outputs rq*4..rq*4+3. Lane l covers K-slice
// p = c*256 + 4l (c=0..3): each x load is 64 lanes x 16B = 1 KB contiguous.
// x is streamed with NONTEMPORAL loads (nt bit): x is 512 MB read-once, and
// L2/L3 line allocation for it is pure overhead. w (reused) stays cached.
__device__ __forceinline__ void fmarow(const vf4* R, const vf4 wreg[4][4],
                                       float p[4]) {
#pragma unroll
    for (int c = 0; c < 4; ++c)
#pragma unroll
        for (int rl = 0; rl < 4; ++rl) {
            p[rl] = fmaf(R[c].x, wreg[c][rl].x, p[rl]);
            p[rl] = fmaf(R[c].y, wreg[c][rl].y, p[rl]);
            p[rl] = fmaf(R[c].z, wreg[c][rl].z, p[rl]);
            p[rl] = fmaf(R[c].w, wreg[c][rl].w, p[rl]);
        }
}

// Exchange-halving butterfly: after it, lane l (l<4) holds output r=l summed
// over all 64 lanes. Register indices static; lane-varying choice via select.
__device__ __forceinline__ void redstore(const float p[4], bool b0, bool b1,
                                         int lane, float* addr) {
    float u01 = b0 ? p[0] : p[1];
    float u23 = b0 ? p[2] : p[3];
    u01 = __shfl_xor(u01, 1);
    u23 = __shfl_xor(u23, 1);
    const float k01 = (b0 ? p[1] : p[0]) + u01;   // holds r = (lane&1)
    const float k23 = (b0 ? p[3] : p[2]) + u23;   // holds r = 2 + (lane&1)
    float u = b1 ? k01 : k23;
    u = __shfl_xor(u, 2);
    float k = (b1 ? k23 : k01) + u;               // holds r = (lane&3)
    k += __shfl_xor(k, 4);
    k += __shfl_xor(k, 8);
    k += __shfl_xor(k, 16);
    k += __shfl_xor(k, 32);
    if (lane < 4) *addr = k;
}

__global__ __launch_bounds__(256, 4)
void MonarchFactor_kernel(const float* __restrict__ x,
                          const float* __restrict__ w,
                          float* __restrict__ out)
{
    const int tid  = threadIdx.x;
    const int rq   = __builtin_amdgcn_readfirstlane(tid >> 6);  // 0..3
    const int lane = tid & 63;
    const int n    = blockIdx.x & 3;
    const long long row0 = (long long)(blockIdx.x >> 2) * ROWS;

    // weights: wreg[c][rl] = w[n][rq*4+rl][c*256 + 4*lane .. +3]  (cached loads)
    vf4 wreg[4][4];
    {
        const float* wb = w + (n * 16 + rq * 4) * 1024 + 4 * lane;
#pragma unroll
        for (int rl = 0; rl < 4; ++rl)
#pragma unroll
            for (int c = 0; c < 4; ++c)
                wreg[c][rl] = *(const vf4*)(wb + rl * 1024 + c * 256);
    }

    const float* xp = x + row0 * IN_F + n * 1024 + 4 * lane;
    float* op = out + row0 * 64 + n * 16 + rq * 4 + lane;  // used when lane<4

    const bool b0 = (lane & 1) != 0;
    const bool b1 = (lane & 2) != 0;

    vf4 A[4], B[4];

#define LOADR(T, R)                                                        \
    {                                                                      \
        const float* xt = xp + (long long)(T) * IN_F;                      \
        _Pragma("unroll")                                                  \
        for (int c = 0; c < 4; ++c)                                        \
            R[c] = __builtin_nontemporal_load((const vf4*)(xt + c * 256)); \
    }

    LOADR(0, A);
    for (int t = 0; t < ROWS; t += 2) {
        LOADR(t + 1, B);
        {
            float p[4] = {0.f, 0.f, 0.f, 0.f};
            fmarow(A, wreg, p);
            redstore(p, b0, b1, lane, op + (long long)t * 64);
        }
        if (t + 2 < ROWS) LOADR(t + 2, A);
        {
            float p[4] = {0.f, 0.f, 0.f, 0.f};
            fmarow(B, wreg, p);
            redstore(p, b0, b1, lane, op + (long long)(t + 1) * 64);
        }
    }
#undef LOADR
}

extern "C" void kernel_launch(void* const* d_in, const int* in_sizes, int n_in,
                              void* d_out, int out_size, void* d_ws, size_t ws_size,
                              hipStream_t stream) {
    const float* x = (const float*)d_in[0];
    const float* w = (const float*)d_in[1];
    float* out = (float*)d_out;

    const int rows   = in_sizes[0] / IN_F;        // 32768
    const int blocks = (rows / ROWS) * 4;         // 256 tiles x 4 n = 1024

    hipLaunchKernelGGL(MonarchFactor_kernel, dim3(blocks), dim3(256), 0, stream,
                       x, w, out);
}

// Round 8
// 138.590 us; speedup vs baseline: 1.4689x; 1.4689x over previous
//
#include <hip/hip_runtime.h>

#define IN_F   4096
#define IN_BLK 1024
#define BLK_R  16
#define CHUNK  32
#define NCH    8               // float4 per row per chunk
#define NITER  32              // IN_BLK / CHUNK

typedef __attribute__((address_space(1))) const void g_void;
typedef __attribute__((address_space(3))) void lds_void;

// r4 (best: 140us) + chunked XCD swizzle (T1). 256 threads = 4 waves; wave n
// owns diagonal block n for the block's 64 rows. x and w staged by
// global_load_lds; LDS dest linear, XOR bank-swizzle applied by permuting the
// per-lane GLOBAL source (write side) and the ds_read index (read side) with
// the same involution. Depth-2 pipeline, counted vmcnt(10), no barriers.
// Swizzle: hw block b (dispatched to XCD b%8) executes original tile-group
// (b%8)*64 + b/8, giving each XCD a contiguous x span and keeping each tile's
// rows in near-linear DRAM order.
__global__ __launch_bounds__(256, 2)
void MonarchFactor_kernel(const float* __restrict__ x,
                          const float* __restrict__ w,
                          float* __restrict__ out)
{
    __shared__ float4 lx[4][2][64 * NCH];      // 64 KiB: x tiles
    __shared__ float4 lw[4][2][BLK_R * NCH];   // 16 KiB: w chunks

    const int tid  = threadIdx.x;
    const int n    = __builtin_amdgcn_readfirstlane(tid >> 6);
    const int lane = tid & 63;

    // chunked XCD swizzle: 512 blocks = 8 XCDs x 64 contiguous
    const int b    = blockIdx.x;
    const int obid = (b & 7) * 64 + (b >> 3);
    const long long row0 = (long long)obid * 64;

    const float* xbase = x + row0 * IN_F + n * IN_BLK;
    const float* wbase = w + n * (BLK_R * IN_BLK);

    // pre-swizzled per-lane global sources (write side of the XOR swizzle)
    const int l3 = lane >> 3, l7 = lane & 7, l5 = lane >> 5;
    // x inst g: slot 64g+l <- x[8g + l3][ l7 ^ l3 ]
    const float* xsrc = xbase + (long long)l3 * IN_F + ((l7 ^ l3) << 2);
    // w inst h: slot 64h+l <- w[8h + l3][ l7 ^ (2h + l5) ]
    const float* wsrc0 = wbase + l3 * IN_BLK + ((l7 ^ l5) << 2);
    const float* wsrc1 = wbase + (8 + l3) * IN_BLK + ((l7 ^ (2 + l5)) << 2);

    // compute decomposition: lane = (rq, rg) -> outputs rq*4+o, rows rg+16j
    const int rq = lane >> 4;
    const int rg = lane & 15;

    float acc[4][4];
#pragma unroll
    for (int j = 0; j < 4; ++j)
#pragma unroll
        for (int o = 0; o < 4; ++o) acc[j][o] = 0.f;

#define ISSUE(T, B)                                                            \
    {                                                                          \
        _Pragma("unroll")                                                      \
        for (int g = 0; g < 8; ++g)                                            \
            __builtin_amdgcn_global_load_lds(                                  \
                (g_void*)(xsrc + (long long)(T) * CHUNK                        \
                               + (long long)(8 * g) * IN_F),                   \
                (lds_void*)&lx[n][B][g * 64], 16, 0, 0);                       \
        __builtin_amdgcn_global_load_lds(                                      \
            (g_void*)(wsrc0 + (T) * CHUNK),                                    \
            (lds_void*)&lw[n][B][0], 16, 0, 0);                                \
        __builtin_amdgcn_global_load_lds(                                      \
            (g_void*)(wsrc1 + (T) * CHUNK),                                    \
            (lds_void*)&lw[n][B][64], 16, 0, 0);                               \
    }

#define COMPUTE(B)                                                             \
    {                                                                          \
        _Pragma("unroll")                                                      \
        for (int c = 0; c < NCH; ++c) {                                        \
            const int sx = c ^ (rg & 7);                                       \
            const int sw = c ^ rq;                                             \
            float4 xv[4], wv[4];                                               \
            _Pragma("unroll")                                                  \
            for (int j = 0; j < 4; ++j)                                        \
                xv[j] = lx[n][B][(rg + 16 * j) * NCH + sx];                    \
            _Pragma("unroll")                                                  \
            for (int o = 0; o < 4; ++o)                                        \
                wv[o] = lw[n][B][(rq * 4 + o) * NCH + sw];                     \
            _Pragma("unroll")                                                  \
            for (int j = 0; j < 4; ++j)                                        \
                _Pragma("unroll")                                              \
                for (int o = 0; o < 4; ++o) {                                  \
                    acc[j][o] = fmaf(xv[j].x, wv[o].x, acc[j][o]);             \
                    acc[j][o] = fmaf(xv[j].y, wv[o].y, acc[j][o]);             \
                    acc[j][o] = fmaf(xv[j].z, wv[o].z, acc[j][o]);             \
                    acc[j][o] = fmaf(xv[j].w, wv[o].w, acc[j][o]);             \
                }                                                              \
        }                                                                      \
    }

#define WAIT10 { asm volatile("s_waitcnt vmcnt(10)" ::: "memory");             \
                 __builtin_amdgcn_sched_barrier(0); }
#define WAIT0  { asm volatile("s_waitcnt vmcnt(0)"  ::: "memory");             \
                 __builtin_amdgcn_sched_barrier(0); }
#define SB     __builtin_amdgcn_sched_barrier(0);

    // prologue: tiles 0,1 in flight
    ISSUE(0, 0);
    ISSUE(1, 1);

    // steady state: wait tile t (10 newest ops belong to t+1), compute, refill.
    for (int t = 0; t < NITER - 2; t += 2) {
        WAIT10; COMPUTE(0); SB; ISSUE(t + 2, 0);
        WAIT10; COMPUTE(1); SB; ISSUE(t + 3, 1);
    }
    WAIT10; COMPUTE(0);      // tile 30
    WAIT0;  COMPUTE(1);      // tile 31

#undef ISSUE
#undef COMPUTE
#undef WAIT10
#undef WAIT0
#undef SB

    // epilogue: lane (rq,rg) holds rows rg+16j, outputs n*16 + rq*4 + o
    float* ob = out + (row0 + rg) * 64 + n * BLK_R + rq * 4;
#pragma unroll
    for (int j = 0; j < 4; ++j) {
        float4 v = make_float4(acc[j][0], acc[j][1], acc[j][2], acc[j][3]);
        *(float4*)(ob + (long long)(16 * j) * 64) = v;
    }
}

extern "C" void kernel_launch(void* const* d_in, const int* in_sizes, int n_in,
                              void* d_out, int out_size, void* d_ws, size_t ws_size,
                              hipStream_t stream) {
    const float* x = (const float*)d_in[0];
    const float* w = (const float*)d_in[1];
    float* out = (float*)d_out;

    const int rows   = in_sizes[0] / IN_F;   // 32768
    const int blocks = rows / 64;            // 512  (= 8 XCDs x 64, swizzle bijective)

    hipLaunchKernelGGL(MonarchFactor_kernel, dim3(blocks), dim3(256), 0, stream,
                       x, w, out);
}